// Round 6
// baseline (561.211 us; speedup 1.0000x reference)
//
#include <hip/hip_runtime.h>
#include <cstddef>

#define NN 100000
#define EE 1600000
#define F_IN 128
#define HID 48
#define NCLS 40
#define EPSV 1e-5f
#define SLOPE 0.01f
#define FIXP 16777216.0f   // 2^24 fixed-point scale for edge weights
#define BLKN 391           // ceil(NN/256)
#define BLKE 6250          // EE/256

typedef _Float16 half4 __attribute__((ext_vector_type(4)));

__device__ inline void fma4(float4& a, float s, const float4 w) {
    a.x += s * w.x; a.y += s * w.y; a.z += s * w.z; a.w += s * w.w;
}

// ---------- device bodies shared by fused + standalone kernels ----------

// mm48: t[r] = dinv[r] * (z[r] @ Wp + rc), fp16 out. sW4/sR must be loaded+synced.
__device__ __forceinline__ void mm48_core(int r, const half4* __restrict__ z,
                                          const float4* sW4, const float* sR,
                                          const float* __restrict__ dinv, half4* __restrict__ t) {
    float4 acc[12];
#pragma unroll
    for (int j = 0; j < 12; j++) {
        acc[j].x = sR[4 * j]; acc[j].y = sR[4 * j + 1];
        acc[j].z = sR[4 * j + 2]; acc[j].w = sR[4 * j + 3];
    }
    const half4* hr = z + (size_t)r * 12;
#pragma unroll 4
    for (int k4 = 0; k4 < 12; k4++) {
        half4 hv = hr[k4];
        float xs[4] = {(float)hv.x, (float)hv.y, (float)hv.z, (float)hv.w};
#pragma unroll
        for (int q = 0; q < 4; q++) {
            int k = k4 * 4 + q;
#pragma unroll
            for (int j = 0; j < 12; j++) fma4(acc[j], xs[q], sW4[k * 12 + j]);
        }
    }
    float di = dinv[r];
    half4* tr = t + (size_t)r * 12;
#pragma unroll
    for (int j = 0; j < 12; j++) {
        half4 o;
        o.x = (_Float16)(acc[j].x * di); o.y = (_Float16)(acc[j].y * di);
        o.z = (_Float16)(acc[j].z * di); o.w = (_Float16)(acc[j].w * di);
        tr[j] = o;
    }
}

// BN stats body: grid-stride over rows with `nblk` stats-blocks, id sb
__device__ __forceinline__ void stats_core(int sb, int nblk, const _Float16* __restrict__ z,
                                           float* __restrict__ stats, float* sS, float* sQ) {
    int tid = threadIdx.x;
    int wid = tid >> 6, lane = tid & 63;
    if (tid < HID) { sS[tid] = 0.f; sQ[tid] = 0.f; }
    __syncthreads();
    if (lane < HID) {
        float s = 0.f, q = 0.f;
        for (int r = sb * 4 + wid; r < NN; r += nblk * 4) {
            float v = (float)z[(size_t)r * HID + lane];
            s += v; q += v * v;
        }
        atomicAdd(&sS[lane], s);
        atomicAdd(&sQ[lane], q);
    }
    __syncthreads();
    if (tid < HID) {
        atomicAdd(&stats[tid], sS[tid]);
        atomicAdd(&stats[HID + tid], sQ[tid]);
    }
}

// ---------- FUSE_A: edge_deg (atomic-bound) || mm1 (VALU-bound) ----------
// grid = 6641: blocks b%17==0 run mm1 (391 of them), others edge_deg (6250).
__global__ __launch_bounds__(256) void f_edge_mm1(const int* __restrict__ ei, const float* __restrict__ ew,
                                                  unsigned long long* __restrict__ packed, int* __restrict__ rank,
                                                  const float* __restrict__ x, const float* __restrict__ W,
                                                  const float* __restrict__ b, half4* __restrict__ z) {
    __shared__ float4 sW4[F_IN * HID / 4];   // 24 KB (only mm1 blocks touch)
    __shared__ float sB[HID];
    int blk = blockIdx.x;
    int tid = threadIdx.x;
    if (blk % 17 != 0) {
        // ---- edge_deg: one u64 atomic per edge; old high word = rank within dst row
        int eb = blk - blk / 17 - 1;
        int e = eb * 256 + tid;
        if (e < EE) {
            int d = ei[EE + e];
            unsigned long long add = (1ULL << 32) | (unsigned long long)__float2uint_rn(ew[e] * FIXP);
            unsigned long long old = atomicAdd(&packed[d], add);
            rank[e] = (int)(old >> 32);
        }
        return;
    }
    // ---- mm1: z = lrelu(x @ W_first + b_first), fp16 out
    int rb = blk / 17;
    const float4* W4 = (const float4*)W;
    for (int i = tid; i < F_IN * HID / 4; i += 256) sW4[i] = W4[i];
    if (tid < HID) sB[tid] = b[tid];
    __syncthreads();
    int r = rb * 256 + tid;
    if (r >= NN) return;
    float4 acc[12];
#pragma unroll
    for (int j = 0; j < 12; j++) {
        acc[j].x = sB[4 * j]; acc[j].y = sB[4 * j + 1];
        acc[j].z = sB[4 * j + 2]; acc[j].w = sB[4 * j + 3];
    }
    const float4* xr = (const float4*)(x + (size_t)r * F_IN);
    for (int k4 = 0; k4 < F_IN / 4; k4++) {
        float4 xv = xr[k4];
        float xs[4] = {xv.x, xv.y, xv.z, xv.w};
#pragma unroll
        for (int q = 0; q < 4; q++) {
            int k = k4 * 4 + q;
#pragma unroll
            for (int j = 0; j < 12; j++) fma4(acc[j], xs[q], sW4[k * 12 + j]);
        }
    }
    half4* zr = z + (size_t)r * 12;
#pragma unroll
    for (int j = 0; j < 12; j++) {
        float4 v = acc[j];
        v.x = v.x >= 0.f ? v.x : SLOPE * v.x;
        v.y = v.y >= 0.f ? v.y : SLOPE * v.y;
        v.z = v.z >= 0.f ? v.z : SLOPE * v.z;
        v.w = v.w >= 0.f ? v.w : SLOPE * v.w;
        half4 o;
        o.x = (_Float16)v.x; o.y = (_Float16)v.y;
        o.z = (_Float16)v.z; o.w = (_Float16)v.w;
        zr[j] = o;
    }
}

// ---------- FUSE_B: scan1+dinv (391 blocks) || stats0 (256 blocks) ----------
__global__ __launch_bounds__(256) void f_scan1_stats(const unsigned long long* __restrict__ packed,
                                                     int* __restrict__ row_start, int* __restrict__ partials,
                                                     float* __restrict__ dinv,
                                                     const _Float16* __restrict__ z0, float* __restrict__ stats) {
    __shared__ int wsum[4];
    __shared__ float sS[HID], sQ[HID];
    int blk = blockIdx.x;
    int tid = threadIdx.x;
    if (blk >= BLKN) {
        stats_core(blk - BLKN, 256, z0, stats, sS, sQ);
        return;
    }
    int i = blk * 256 + tid;
    unsigned long long p = (i < NN) ? packed[i] : 0ULL;
    int v = (int)(p >> 32);
    if (i < NN) {
        float wdeg = (float)(unsigned int)(p & 0xffffffffULL) * (1.0f / FIXP);
        dinv[i] = rsqrtf(wdeg + 1.0f);   // +1 = self-loop weight; always > 0
    }
    int lane = tid & 63, w = tid >> 6;
    int incl = v;
#pragma unroll
    for (int off = 1; off < 64; off <<= 1) {
        int t = __shfl_up(incl, off);
        if (lane >= off) incl += t;
    }
    if (lane == 63) wsum[w] = incl;
    __syncthreads();
    int base = 0;
#pragma unroll
    for (int j = 0; j < 3; j++) base += (j < w) ? wsum[j] : 0;
    if (i < NN) row_start[i] = base + incl - v;
    if (tid == 255) partials[blk] = base + incl;
}

// ---------- FUSE_C: scan2 (block 0) || bn_fold1 (block 1); 512 threads ----------
__global__ __launch_bounds__(512) void f_scan2_fold(const int* __restrict__ partials, int* __restrict__ p_off,
                                                    const float* __restrict__ stats, const float* __restrict__ g,
                                                    const float* __restrict__ b, const float* __restrict__ W,
                                                    float* __restrict__ ac, float* __restrict__ Wp,
                                                    float* __restrict__ rc) {
    __shared__ int wsum[8];
    __shared__ float sA[HID], sC[HID];
    int tid = threadIdx.x;
    if (blockIdx.x == 0) {
        int v = (tid < BLKN) ? partials[tid] : 0;
        int lane = tid & 63, w = tid >> 6;
        int incl = v;
#pragma unroll
        for (int off = 1; off < 64; off <<= 1) {
            int t = __shfl_up(incl, off);
            if (lane >= off) incl += t;
        }
        if (lane == 63) wsum[w] = incl;
        __syncthreads();
        int base = 0;
#pragma unroll
        for (int j = 0; j < 7; j++) base += (j < w) ? wsum[j] : 0;
        if (tid < BLKN) p_off[tid] = base + incl - v;
        return;
    }
    // bn_fold: a,c from stats; Wp[k][j]=a[k]W[k][j]; rc[j]=sum_k c[k]W[k][j]
    if (tid < HID) {
        float mean = stats[tid] * (1.0f / (float)NN);
        float var = stats[HID + tid] * (1.0f / (float)NN) - mean * mean;
        float a = g[tid] * rsqrtf(var + EPSV);
        float c = b[tid] - mean * a;
        sA[tid] = a; sC[tid] = c;
        ac[tid] = a; ac[HID + tid] = c;
    }
    __syncthreads();
    for (int i = tid; i < HID * HID; i += 512) Wp[i] = sA[i / HID] * W[i];
    if (tid < HID) {
        float acc = 0.f;
        for (int k = 0; k < HID; k++) acc += sC[k] * W[k * HID + tid];
        rc[tid] = acc;
    }
}

// ---------- FUSE_D: scan3 (391) || mm48#1 (391) ----------
__global__ __launch_bounds__(256) void f_scan3_mm48(int* __restrict__ row_start, const int* __restrict__ p_off,
                                                    const half4* __restrict__ z, const float* __restrict__ Wp,
                                                    const float* __restrict__ rc, const float* __restrict__ dinv,
                                                    half4* __restrict__ t) {
    __shared__ float4 sW4[HID * HID / 4];
    __shared__ float sR[HID];
    int blk = blockIdx.x;
    int tid = threadIdx.x;
    if (blk < BLKN) {
        int i = blk * 256 + tid;
        if (i < NN) row_start[i] += p_off[blk];
        if (i == 0) row_start[NN] = EE;
        return;
    }
    const float4* W4 = (const float4*)Wp;
    for (int i = tid; i < HID * HID / 4; i += 256) sW4[i] = W4[i];
    if (tid < HID) sR[tid] = rc[tid];
    __syncthreads();
    int r = (blk - BLKN) * 256 + tid;
    if (r >= NN) return;
    mm48_core(r, z, sW4, sR, dinv, t);
}

// standalone mm48 (conv 2)
__global__ __launch_bounds__(256) void k_mm48(const half4* __restrict__ z, const float* __restrict__ Wp,
                                              const float* __restrict__ rc, const float* __restrict__ dinv,
                                              half4* __restrict__ t) {
    __shared__ float4 sW4[HID * HID / 4];
    __shared__ float sR[HID];
    int tid = threadIdx.x;
    const float4* W4 = (const float4*)Wp;
    for (int i = tid; i < HID * HID / 4; i += 256) sW4[i] = W4[i];
    if (tid < HID) sR[tid] = rc[tid];
    __syncthreads();
    int r = blockIdx.x * 256 + tid;
    if (r >= NN) return;
    mm48_core(r, z, sW4, sR, dinv, t);
}

// standalone stats
__global__ __launch_bounds__(256) void k_stats(const _Float16* __restrict__ z, float* __restrict__ stats) {
    __shared__ float sS[HID], sQ[HID];
    stats_core(blockIdx.x, 256, z, stats, sS, sQ);
}

// standalone bn_fold (conv 2)
__global__ __launch_bounds__(256) void k_bn_fold(const float* __restrict__ stats, const float* __restrict__ g,
                                                 const float* __restrict__ b, const float* __restrict__ W,
                                                 float* __restrict__ ac, float* __restrict__ Wp,
                                                 float* __restrict__ rc) {
    __shared__ float sA[HID], sC[HID];
    int tid = threadIdx.x;
    if (tid < HID) {
        float mean = stats[tid] * (1.0f / (float)NN);
        float var = stats[HID + tid] * (1.0f / (float)NN) - mean * mean;
        float a = g[tid] * rsqrtf(var + EPSV);
        float c = b[tid] - mean * a;
        sA[tid] = a; sC[tid] = c;
        ac[tid] = a; ac[HID + tid] = c;
    }
    __syncthreads();
    for (int i = tid; i < HID * HID; i += 256) Wp[i] = sA[i / HID] * W[i];
    if (tid < HID) {
        float acc = 0.f;
        for (int k = 0; k < HID; k++) acc += sC[k] * W[k * HID + tid];
        rc[tid] = acc;
    }
}

// atomic-free scatter: pos = row_start[d] + rank[e]; es = (src, raw edge weight)
__global__ void k_scatter(const int* __restrict__ ei, const float* __restrict__ ew,
                          const int* __restrict__ row_start, const int* __restrict__ rank,
                          float2* __restrict__ es) {
    int e = blockIdx.x * 256 + threadIdx.x;
    if (e < EE) {
        int s = ei[e];
        int d = ei[EE + e];
        int pos = row_start[d] + rank[e];
        es[pos] = make_float2(__int_as_float(s), ew[e]);
    }
}

// aggregation with dinv folded into table: z[n] = lrelu( dinv[n]*(t'[n] + sum_e ew*t'[src]) + bias )
// one wave per dst row; 4 groups x 16 lanes (12 active, half4 gathers); meta + row depth-1 prefetch.
__global__ __launch_bounds__(256) void k_agg(const half4* __restrict__ hw, const int* __restrict__ row_start,
                                             const float2* __restrict__ es, const float* __restrict__ dinv,
                                             const float* __restrict__ bias, half4* __restrict__ z) {
    int n = blockIdx.x * 4 + (threadIdx.x >> 6);
    int lane = threadIdx.x & 63;
    int g = lane >> 4, sub = lane & 15;
    bool act = sub < 12;
    float4 acc = make_float4(0.f, 0.f, 0.f, 0.f);
    if (g == 0 && act) {
        half4 v = hw[(size_t)n * 12 + sub];           // t'[n], self-loop weight 1
        acc.x = (float)v.x; acc.y = (float)v.y;
        acc.z = (float)v.z; acc.w = (float)v.w;
    }
    int e0 = row_start[n], e1 = row_start[n + 1];
    int eg = e0 + g;
    float2 meta = (eg < e1) ? es[eg] : make_float2(0.f, 0.f);
    half4 row = {(_Float16)0, (_Float16)0, (_Float16)0, (_Float16)0};
    if (act && eg < e1) row = hw[(size_t)__float_as_int(meta.x) * 12 + sub];
    for (int e = e0; e < e1; e += 4) {
        float w = meta.y;
        half4 cur = row;
        bool valid = (e + g < e1);
        int egn = e + 4 + g;
        meta = (egn < e1) ? es[egn] : make_float2(0.f, 0.f);
        if (act && egn < e1) row = hw[(size_t)__float_as_int(meta.x) * 12 + sub];  // prefetch next
        if (act && valid) {
            acc.x += w * (float)cur.x; acc.y += w * (float)cur.y;
            acc.z += w * (float)cur.z; acc.w += w * (float)cur.w;
        }
    }
#pragma unroll
    for (int off = 16; off <= 32; off <<= 1) {
        acc.x += __shfl_xor(acc.x, off);
        acc.y += __shfl_xor(acc.y, off);
        acc.z += __shfl_xor(acc.z, off);
        acc.w += __shfl_xor(acc.w, off);
    }
    if (g == 0 && act) {
        float di = dinv[n];
        const float4* b4 = (const float4*)bias;
        float4 bv = b4[sub];
        float4 v;
        v.x = di * acc.x + bv.x; v.y = di * acc.y + bv.y;
        v.z = di * acc.z + bv.z; v.w = di * acc.w + bv.w;
        v.x = v.x >= 0.f ? v.x : SLOPE * v.x;
        v.y = v.y >= 0.f ? v.y : SLOPE * v.y;
        v.z = v.z >= 0.f ? v.z : SLOPE * v.z;
        v.w = v.w >= 0.f ? v.w : SLOPE * v.w;
        half4 o;
        o.x = (_Float16)v.x; o.y = (_Float16)v.y;
        o.z = (_Float16)v.z; o.w = (_Float16)v.w;
        z[(size_t)n * 12 + sub] = o;
    }
}

// fold BN1/BN2 (from ac) and BN3 (from stats2) into W_out: Wp[144][40], bc[40]
__global__ __launch_bounds__(256) void k_fold_final(const float* __restrict__ ac0, const float* __restrict__ ac1,
                                                    const float* __restrict__ stats2, const float* __restrict__ g3,
                                                    const float* __restrict__ b3, const float* __restrict__ W,
                                                    const float* __restrict__ b, float* __restrict__ Wp,
                                                    float* __restrict__ bc) {
    __shared__ float sA[3 * HID], sC[3 * HID];
    int tid = threadIdx.x;
    if (tid < 96) {
        const float* a = (tid < HID) ? ac0 : ac1;
        int j = tid % HID;
        sA[tid] = a[j]; sC[tid] = a[HID + j];
    } else if (tid < 144) {
        int j = tid - 96;
        float mean = stats2[j] * (1.0f / (float)NN);
        float var = stats2[HID + j] * (1.0f / (float)NN) - mean * mean;
        float a = g3[j] * rsqrtf(var + EPSV);
        sA[tid] = a; sC[tid] = b3[j] - mean * a;
    }
    __syncthreads();
    for (int i = tid; i < 3 * HID * NCLS; i += 256) Wp[i] = sA[i / NCLS] * W[i];
    if (tid < NCLS) {
        float acc = b[tid];
        for (int k = 0; k < 3 * HID; k++) acc += sC[k] * W[k * NCLS + tid];
        bc[tid] = acc;
    }
}

// output layer (fp16 z inputs; BN folded into Wp/bc) + log_softmax
__global__ __launch_bounds__(256) void k_final(const half4* __restrict__ z0, const half4* __restrict__ z1,
                                               const half4* __restrict__ z2, const float* __restrict__ Wp,
                                               const float* __restrict__ bc, float* __restrict__ out) {
    __shared__ float4 sW4[3 * HID * NCLS / 4];   // 23 KB
    __shared__ float sB[NCLS];
    int tid = threadIdx.x;
    const float4* W4 = (const float4*)Wp;
    for (int i = tid; i < 3 * HID * NCLS / 4; i += 256) sW4[i] = W4[i];
    if (tid < NCLS) sB[tid] = bc[tid];
    __syncthreads();
    int r = blockIdx.x * 256 + tid;
    if (r >= NN) return;
    float4 acc[10];
#pragma unroll
    for (int j = 0; j < 10; j++) {
        acc[j].x = sB[4 * j]; acc[j].y = sB[4 * j + 1];
        acc[j].z = sB[4 * j + 2]; acc[j].w = sB[4 * j + 3];
    }
    const half4* zs[3] = {z0, z1, z2};
#pragma unroll
    for (int part = 0; part < 3; part++) {
        const half4* hr = zs[part] + (size_t)r * 12;
        for (int k4 = 0; k4 < 12; k4++) {
            half4 hv = hr[k4];
            float xs[4] = {(float)hv.x, (float)hv.y, (float)hv.z, (float)hv.w};
#pragma unroll
            for (int q = 0; q < 4; q++) {
                int k = part * HID + k4 * 4 + q;
#pragma unroll
                for (int j = 0; j < 10; j++) fma4(acc[j], xs[q], sW4[k * 10 + j]);
            }
        }
    }
    float m = -1e30f;
#pragma unroll
    for (int j = 0; j < 10; j++)
        m = fmaxf(m, fmaxf(fmaxf(acc[j].x, acc[j].y), fmaxf(acc[j].z, acc[j].w)));
    float s = 0.f;
#pragma unroll
    for (int j = 0; j < 10; j++)
        s += __expf(acc[j].x - m) + __expf(acc[j].y - m) + __expf(acc[j].z - m) + __expf(acc[j].w - m);
    float l = m + __logf(s);
    float4* orow = (float4*)(out + (size_t)r * NCLS);
#pragma unroll
    for (int j = 0; j < 10; j++) {
        float4 v = acc[j];
        v.x -= l; v.y -= l; v.z -= l; v.w -= l;
        orow[j] = v;
    }
}

// ---------- launch ----------

extern "C" void kernel_launch(void* const* d_in, const int* in_sizes, int n_in,
                              void* d_out, int out_size, void* d_ws, size_t ws_size,
                              hipStream_t stream) {
    const float* x       = (const float*)d_in[0];
    const int*   ei      = (const int*)d_in[1];
    const float* ew      = (const float*)d_in[2];
    const float* W_first = (const float*)d_in[3];
    const float* b_first = (const float*)d_in[4];
    const float* bn1_g   = (const float*)d_in[5];
    const float* bn1_b   = (const float*)d_in[6];
    const float* Wc1     = (const float*)d_in[7];
    const float* bc1     = (const float*)d_in[8];
    const float* bn2_g   = (const float*)d_in[9];
    const float* bn2_b   = (const float*)d_in[10];
    const float* Wc2     = (const float*)d_in[11];
    const float* bc2     = (const float*)d_in[12];
    const float* bn3_g   = (const float*)d_in[13];
    const float* bn3_b   = (const float*)d_in[14];
    const float* W_out   = (const float*)d_in[15];
    const float* b_out   = (const float*)d_in[16];
    float* out = (float*)d_out;

    // workspace layout — packed+stats adjacent for one memset
    char* wsb = (char*)d_ws;
    _Float16* z0h = (_Float16*)wsb;                         // N*48 fp16
    _Float16* z1h = z0h + (size_t)NN * HID;
    _Float16* z2h = z1h + (size_t)NN * HID;
    _Float16* tbh = z2h + (size_t)NN * HID;                 // dinv-scaled gather table fp16
    unsigned long long* packed = (unsigned long long*)(tbh + (size_t)NN * HID);  // N u64
    float* stats  = (float*)(packed + NN);                  // 3*96 (zeroed with packed)
    float* dinv   = stats + 288;                            // N
    int*   rank   = (int*)(dinv + NN);                      // E
    int*   row_st = rank + EE;                              // N+4
    float2* es    = (float2*)(row_st + NN + 4);             // E float2 (src, ew)
    float* ac     = (float*)(es + EE);                      // 2*96 (BN1, BN2 a/c)
    float* Wp1    = ac + 192;                               // 2304
    float* rc1    = Wp1 + HID * HID;                        // 48
    float* Wp2    = rc1 + HID;                              // 2304
    float* rc2    = Wp2 + HID * HID;                        // 48
    float* WpO    = rc2 + HID;                              // 5760
    float* bcO    = WpO + 3 * HID * NCLS;                   // 40 (+pad)
    int*   partials = (int*)(bcO + 40 + 8);                 // 512
    int*   p_off  = partials + 512;                         // 512

    hipMemsetAsync(packed, 0, sizeof(unsigned long long) * NN + sizeof(float) * 288, stream);

    // FUSE_A: edge histogram (6250 atomic-bound blocks) || mm1 (391 VALU blocks), 17:1 interleave
    f_edge_mm1<<<BLKE + BLKN, 256, 0, stream>>>(ei, ew, packed, rank, x, W_first, b_first, (half4*)z0h);
    // FUSE_B: scan1+dinv || BN1 stats
    f_scan1_stats<<<BLKN + 256, 256, 0, stream>>>(packed, row_st, partials, dinv, z0h, stats);
    // FUSE_C: scan2 || bn_fold1
    f_scan2_fold<<<2, 512, 0, stream>>>(partials, p_off, stats, bn1_g, bn1_b, Wc1, ac, Wp1, rc1);
    // FUSE_D: scan3 || mm48#1 (writes dinv-scaled fp16 table)
    f_scan3_mm48<<<2 * BLKN, 256, 0, stream>>>(row_st, p_off, (const half4*)z0h, Wp1, rc1, dinv, (half4*)tbh);
    // scatter (atomic-free, no dinv gather)
    k_scatter<<<BLKE, 256, 0, stream>>>(ei, ew, row_st, rank, es);

    // conv 1
    k_agg<<<NN / 4, 256, 0, stream>>>((const half4*)tbh, row_st, es, dinv, bc1, (half4*)z1h);
    k_stats<<<256, 256, 0, stream>>>(z1h, stats + 96);
    k_bn_fold<<<1, 256, 0, stream>>>(stats + 96, bn2_g, bn2_b, Wc2, ac + 96, Wp2, rc2);

    // conv 2
    k_mm48<<<BLKN, 256, 0, stream>>>((const half4*)z1h, Wp2, rc2, dinv, (half4*)tbh);
    k_agg<<<NN / 4, 256, 0, stream>>>((const half4*)tbh, row_st, es, dinv, bc2, (half4*)z2h);
    k_stats<<<256, 256, 0, stream>>>(z2h, stats + 192);

    // fold BN1/2/3 into output weights; final layer + log_softmax
    k_fold_final<<<1, 256, 0, stream>>>(ac, ac + 96, stats + 192, bn3_g, bn3_b, W_out, b_out, WpO, bcO);
    k_final<<<BLKN, 256, 0, stream>>>((const half4*)z0h, (const half4*)z1h, (const half4*)z2h, WpO, bcO, out);
}

// Round 7
// 540.470 us; speedup vs baseline: 1.0384x; 1.0384x over previous
//
#include <hip/hip_runtime.h>
#include <cstddef>

#define NN 100000
#define EE 1600000
#define F_IN 128
#define HID 48
#define NCLS 40
#define EPSV 1e-5f
#define SLOPE 0.01f
#define FIXP 16777216.0f   // 2^24 fixed-point scale for degree accumulation
#define BLKN 391           // ceil(NN/256)
#define BLKE 6250          // EE/256
#define NSTAT 256          // stats blocks

typedef _Float16 half4 __attribute__((ext_vector_type(4)));
typedef _Float16 half8 __attribute__((ext_vector_type(8)));

__device__ inline void fma4(float4& a, float s, const float4 w) {
    a.x += s * w.x; a.y += s * w.y; a.z += s * w.z; a.w += s * w.w;
}
__device__ inline float4 scale4(float4 w, float a) {
    return make_float4(w.x * a, w.y * a, w.z * a, w.w * a);
}

// ---------- shared device bodies ----------

// mm48 core: t[r] = dinv[r] * (z[r] @ sW + sR)
__device__ __forceinline__ void mm48_core(int r, const half4* __restrict__ z,
                                          const float4* sW4, const float* sR,
                                          const float* __restrict__ dinv, half4* __restrict__ t) {
    float4 acc[12];
#pragma unroll
    for (int j = 0; j < 12; j++) {
        acc[j].x = sR[4 * j]; acc[j].y = sR[4 * j + 1];
        acc[j].z = sR[4 * j + 2]; acc[j].w = sR[4 * j + 3];
    }
    const half4* hr = z + (size_t)r * 12;
#pragma unroll 4
    for (int k4 = 0; k4 < 12; k4++) {
        half4 hv = hr[k4];
        float xs[4] = {(float)hv.x, (float)hv.y, (float)hv.z, (float)hv.w};
#pragma unroll
        for (int q = 0; q < 4; q++) {
            int k = k4 * 4 + q;
#pragma unroll
            for (int j = 0; j < 12; j++) fma4(acc[j], xs[q], sW4[k * 12 + j]);
        }
    }
    float di = dinv[r];
    half4* tr = t + (size_t)r * 12;
#pragma unroll
    for (int j = 0; j < 12; j++) {
        half4 o;
        o.x = (_Float16)(acc[j].x * di); o.y = (_Float16)(acc[j].y * di);
        o.z = (_Float16)(acc[j].z * di); o.w = (_Float16)(acc[j].w * di);
        tr[j] = o;
    }
}

// inline BN fold: a,c from stats; sW4 = diag(a)W (float4), sR = c^T W
__device__ __forceinline__ void bn_fold_prologue(const float* __restrict__ stats, const float* __restrict__ g,
                                                 const float* __restrict__ b, const float* __restrict__ W,
                                                 float4* sW4, float* sR, float* sA, float* sC) {
    int tid = threadIdx.x;
    if (tid < HID) {
        float mean = stats[tid] * (1.0f / (float)NN);
        float var = stats[HID + tid] * (1.0f / (float)NN) - mean * mean;
        float a = g[tid] * rsqrtf(var + EPSV);
        sA[tid] = a; sC[tid] = b[tid] - mean * a;
    }
    __syncthreads();
    const float4* W4 = (const float4*)W;
    for (int i = tid; i < HID * HID / 4; i += 256) sW4[i] = scale4(W4[i], sA[i / 12]);
    if (tid < HID) {
        float acc = 0.f;
        for (int k = 0; k < HID; k++) acc += sC[k] * W[k * HID + tid];
        sR[tid] = acc;
    }
    __syncthreads();
}

// BN stats body
__device__ __forceinline__ void stats_core(int sb, int nblk, const _Float16* __restrict__ z,
                                           float* __restrict__ stats, float* sS, float* sQ) {
    int tid = threadIdx.x;
    int wid = tid >> 6, lane = tid & 63;
    if (tid < HID) { sS[tid] = 0.f; sQ[tid] = 0.f; }
    __syncthreads();
    if (lane < HID) {
        float s = 0.f, q = 0.f;
        for (int r = sb * 4 + wid; r < NN; r += nblk * 4) {
            float v = (float)z[(size_t)r * HID + lane];
            s += v; q += v * v;
        }
        atomicAdd(&sS[lane], s);
        atomicAdd(&sQ[lane], q);
    }
    __syncthreads();
    if (tid < HID) {
        atomicAdd(&stats[tid], sS[tid]);
        atomicAdd(&stats[HID + tid], sQ[tid]);
    }
}

// ---------- FUSE_A: edge histogram (atomic-bound) || mm1 (VALU-bound), ZERO LDS ----------
// grid 6641; blocks b%17==0 are mm1 (391), others edge_deg (6250).
__global__ __launch_bounds__(256) void f_edge_mm1(const int* __restrict__ ei, const float* __restrict__ ew,
                                                  unsigned long long* __restrict__ packed, int* __restrict__ rank,
                                                  const float* __restrict__ x, const float* __restrict__ W,
                                                  const float* __restrict__ b, half4* __restrict__ z) {
    int blk = blockIdx.x, tid = threadIdx.x;
    if (blk % 17 != 0) {
        int eb = blk - blk / 17 - 1;
        int e = eb * 256 + tid;
        if (e < EE) {
            int d = ei[EE + e];
            unsigned long long add = (1ULL << 32) | (unsigned long long)__float2uint_rn(ew[e] * FIXP);
            unsigned long long old = atomicAdd(&packed[d], add);
            rank[e] = (int)(old >> 32);
        }
        return;
    }
    int r = (blk / 17) * 256 + tid;
    if (r >= NN) return;
    const float4* W4 = (const float4*)W;   // weights via global/L1 broadcast (no LDS!)
    float4 acc[12];
#pragma unroll
    for (int j = 0; j < 12; j++) {
        acc[j].x = b[4 * j]; acc[j].y = b[4 * j + 1];
        acc[j].z = b[4 * j + 2]; acc[j].w = b[4 * j + 3];
    }
    const float4* xr = (const float4*)(x + (size_t)r * F_IN);
    for (int k4 = 0; k4 < F_IN / 4; k4++) {
        float4 xv = xr[k4];
        float xs[4] = {xv.x, xv.y, xv.z, xv.w};
#pragma unroll
        for (int q = 0; q < 4; q++) {
            int k = k4 * 4 + q;
#pragma unroll
            for (int j = 0; j < 12; j++) fma4(acc[j], xs[q], W4[k * 12 + j]);
        }
    }
    half4* zr = z + (size_t)r * 12;
#pragma unroll
    for (int j = 0; j < 12; j++) {
        float4 v = acc[j];
        v.x = v.x >= 0.f ? v.x : SLOPE * v.x;
        v.y = v.y >= 0.f ? v.y : SLOPE * v.y;
        v.z = v.z >= 0.f ? v.z : SLOPE * v.z;
        v.w = v.w >= 0.f ? v.w : SLOPE * v.w;
        half4 o;
        o.x = (_Float16)v.x; o.y = (_Float16)v.y;
        o.z = (_Float16)v.z; o.w = (_Float16)v.w;
        zr[j] = o;
    }
}

// ---------- FUSE_B: single-kernel decoupled-lookback scan (+dinv) || BN1 stats ----------
// tickets order the scan blocks; grid = BLKN + NSTAT.
__global__ __launch_bounds__(256) void f_scan_stats(const unsigned long long* __restrict__ packed,
                                                    int* __restrict__ row_start, float* __restrict__ dinv,
                                                    unsigned* __restrict__ status, unsigned* __restrict__ ticket,
                                                    const _Float16* __restrict__ z0, float* __restrict__ stats) {
    __shared__ float sS[HID], sQ[HID];
    __shared__ int wsum[4];
    __shared__ int sPrefix;
    __shared__ unsigned sTicket;
    int tid = threadIdx.x;
    if (tid == 0) sTicket = atomicAdd(ticket, 1u);
    __syncthreads();
    int t = (int)sTicket;
    if (t >= BLKN) {                       // stats role
        stats_core(t - BLKN, NSTAT, z0, stats, sS, sQ);
        return;
    }
    int i = t * 256 + tid;
    unsigned long long p = (i < NN) ? packed[i] : 0ULL;
    int v = (int)(p >> 32);
    if (i < NN) {
        float wdeg = (float)(unsigned int)(p & 0xffffffffULL) * (1.0f / FIXP);
        dinv[i] = rsqrtf(wdeg + 1.0f);     // +1 self-loop; always > 0
    }
    int lane = tid & 63, w = tid >> 6;
    int incl = v;
#pragma unroll
    for (int off = 1; off < 64; off <<= 1) {
        int tt = __shfl_up(incl, off);
        if (lane >= off) incl += tt;
    }
    if (lane == 63) wsum[w] = incl;
    __syncthreads();
    int base = 0;
#pragma unroll
    for (int j = 0; j < 3; j++) base += (j < w) ? wsum[j] : 0;
    int total = wsum[0] + wsum[1] + wsum[2] + wsum[3];
    // publish aggregate (or prefix for block 0)
    if (tid == 0) {
        unsigned word = (t == 0) ? ((2u << 30) | (unsigned)total) : ((1u << 30) | (unsigned)total);
        __hip_atomic_store(&status[t], word, __ATOMIC_RELEASE, __HIP_MEMORY_SCOPE_AGENT);
    }
    // wave-parallel lookback
    if (t == 0) {
        if (tid == 0) sPrefix = 0;
    } else if (tid < 64) {
        int run = 0, j = t - 1;
        while (true) {
            int idx = j - tid;
            unsigned wd = (idx >= 0)
                ? __hip_atomic_load(&status[idx], __ATOMIC_ACQUIRE, __HIP_MEMORY_SCOPE_AGENT)
                : (2u << 30);
            bool ready = (wd >> 30) != 0u;
            if (!__all(ready)) continue;
            unsigned long long pmask = __ballot((wd >> 30) == 2u);
            int stop = pmask ? (__ffsll((long long)pmask) - 1) : 64;
            int val = (tid <= stop) ? (int)(wd & 0x3FFFFFFFu) : 0;
#pragma unroll
            for (int off = 1; off < 64; off <<= 1) val += __shfl_xor(val, off);
            run += val;
            if (stop < 64) break;
            j -= 64;
        }
        if (tid == 0) {
            sPrefix = run;
            __hip_atomic_store(&status[t], (2u << 30) | (unsigned)(run + total),
                               __ATOMIC_RELEASE, __HIP_MEMORY_SCOPE_AGENT);
        }
    }
    __syncthreads();
    int pref = sPrefix;
    if (i < NN) row_start[i] = pref + base + incl - v;
    if (t == BLKN - 1 && tid == 255) row_start[NN] = EE;
}

// ---------- FUSE_C: scatter (write-bound) || mm48#1 with inline BN1 fold ----------
__global__ __launch_bounds__(256) void f_scatter_mm48(const int* __restrict__ ei, const float* __restrict__ ew,
                                                      const int* __restrict__ row_start, const int* __restrict__ rank,
                                                      unsigned* __restrict__ es,
                                                      const float* __restrict__ stats, const float* __restrict__ g,
                                                      const float* __restrict__ bb, const float* __restrict__ W,
                                                      const half4* __restrict__ z, const float* __restrict__ dinv,
                                                      half4* __restrict__ t) {
    __shared__ float4 sW4[HID * HID / 4];   // 9.2 KB
    __shared__ float sR[HID], sA[HID], sC[HID];
    int blk = blockIdx.x, tid = threadIdx.x;
    if (blk < BLKE) {
        int e = blk * 256 + tid;
        if (e < EE) {
            int s = ei[e], d = ei[EE + e];
            unsigned wq = (unsigned)(ew[e] * 32768.0f);
            if (wq > 32767u) wq = 32767u;
            es[row_start[d] + rank[e]] = ((unsigned)s << 15) | wq;   // src:17b | ew:15b
        }
        return;
    }
    bn_fold_prologue(stats, g, bb, W, sW4, sR, sA, sC);
    int r = (blk - BLKE) * 256 + tid;
    if (r >= NN) return;
    mm48_core(r, z, sW4, sR, dinv, t);
}

// standalone mm48 (conv 2) with inline BN2 fold
__global__ __launch_bounds__(256) void k_mm48(const float* __restrict__ stats, const float* __restrict__ g,
                                              const float* __restrict__ bb, const float* __restrict__ W,
                                              const half4* __restrict__ z, const float* __restrict__ dinv,
                                              half4* __restrict__ t) {
    __shared__ float4 sW4[HID * HID / 4];
    __shared__ float sR[HID], sA[HID], sC[HID];
    bn_fold_prologue(stats, g, bb, W, sW4, sR, sA, sC);
    int r = blockIdx.x * 256 + threadIdx.x;
    if (r >= NN) return;
    mm48_core(r, z, sW4, sR, dinv, t);
}

// standalone stats
__global__ __launch_bounds__(256) void k_stats(const _Float16* __restrict__ z, float* __restrict__ stats) {
    __shared__ float sS[HID], sQ[HID];
    stats_core(blockIdx.x, NSTAT, z, stats, sS, sQ);
}

// aggregation: z[n] = lrelu( dinv[n]*(t'[n] + sum_e ew*t'[src]) + bias ), t' = dinv-scaled table
// one wave per dst row; 8 groups x 8 lanes (6 active, half8 = 16B gathers); depth-1 prefetch.
__global__ __launch_bounds__(256) void k_agg(const half8* __restrict__ hw, const int* __restrict__ row_start,
                                             const unsigned* __restrict__ es, const float* __restrict__ dinv,
                                             const float* __restrict__ bias, half8* __restrict__ z) {
    int n = blockIdx.x * 4 + (threadIdx.x >> 6);
    int lane = threadIdx.x & 63;
    int g = lane >> 3, sub = lane & 7;
    bool act = sub < 6;
    float acc[8];
#pragma unroll
    for (int c = 0; c < 8; c++) acc[c] = 0.f;
    if (g == 0 && act) {
        half8 v = hw[(size_t)n * 6 + sub];          // self term, weight 1 (dinv folded in table)
#pragma unroll
        for (int c = 0; c < 8; c++) acc[c] = (float)v[c];
    }
    int e0 = row_start[n], e1 = row_start[n + 1];
    int e = e0 + g;
    unsigned meta = (e < e1) ? es[e] : 0u;
    half8 row = {};
    if (act && e < e1) row = hw[(size_t)(meta >> 15) * 6 + sub];
    for (int base = e0; base < e1; base += 8) {
        bool valid = (base + g < e1);
        float w = (float)(meta & 0x7fffu) * (1.0f / 32768.0f);
        half8 cur = row;
        int en = base + 8 + g;
        meta = (en < e1) ? es[en] : 0u;
        if (act && en < e1) row = hw[(size_t)(meta >> 15) * 6 + sub];   // prefetch next
        if (act && valid) {
#pragma unroll
            for (int c = 0; c < 8; c++) acc[c] += w * (float)cur[c];
        }
    }
#pragma unroll
    for (int off = 8; off <= 32; off <<= 1) {
#pragma unroll
        for (int c = 0; c < 8; c++) acc[c] += __shfl_xor(acc[c], off);
    }
    if (g == 0 && act) {
        float di = dinv[n];
        half8 o;
#pragma unroll
        for (int c = 0; c < 8; c++) {
            float v = di * acc[c] + bias[sub * 8 + c];
            v = v >= 0.f ? v : SLOPE * v;
            o[c] = (_Float16)v;
        }
        z[(size_t)n * 6 + sub] = o;
    }
}

// output layer: folds BN1/2/3 inline from raw stats, then [N,144]@[144,40] + log_softmax
__global__ __launch_bounds__(256) void k_final(const half4* __restrict__ z0, const half4* __restrict__ z1,
                                               const half4* __restrict__ z2, const float* __restrict__ stats,
                                               const float* __restrict__ g1, const float* __restrict__ b1,
                                               const float* __restrict__ g2, const float* __restrict__ b2,
                                               const float* __restrict__ g3, const float* __restrict__ b3,
                                               const float* __restrict__ W, const float* __restrict__ b,
                                               float* __restrict__ out) {
    __shared__ float4 sW4[3 * HID * NCLS / 4];   // 23 KB
    __shared__ float sB[NCLS], sA[3 * HID], sC[3 * HID];
    int tid = threadIdx.x;
    if (tid < 3 * HID) {
        int layer = tid / HID, j = tid % HID;
        const float* st = stats + 96 * layer;
        const float* gg = layer == 0 ? g1 : layer == 1 ? g2 : g3;
        const float* bv = layer == 0 ? b1 : layer == 1 ? b2 : b3;
        float mean = st[j] * (1.0f / (float)NN);
        float var = st[HID + j] * (1.0f / (float)NN) - mean * mean;
        float a = gg[j] * rsqrtf(var + EPSV);
        sA[tid] = a; sC[tid] = bv[j] - mean * a;
    }
    __syncthreads();
    const float4* W4 = (const float4*)W;
    for (int i = tid; i < 3 * HID * NCLS / 4; i += 256) sW4[i] = scale4(W4[i], sA[i / 10]);
    if (tid < NCLS) {
        float acc = b[tid];
        for (int k = 0; k < 3 * HID; k++) acc += sC[k] * W[k * NCLS + tid];
        sB[tid] = acc;
    }
    __syncthreads();
    int r = blockIdx.x * 256 + tid;
    if (r >= NN) return;
    float4 acc[10];
#pragma unroll
    for (int j = 0; j < 10; j++) {
        acc[j].x = sB[4 * j]; acc[j].y = sB[4 * j + 1];
        acc[j].z = sB[4 * j + 2]; acc[j].w = sB[4 * j + 3];
    }
    const half4* zs[3] = {z0, z1, z2};
#pragma unroll
    for (int part = 0; part < 3; part++) {
        const half4* hr = zs[part] + (size_t)r * 12;
        for (int k4 = 0; k4 < 12; k4++) {
            half4 hv = hr[k4];
            float xs[4] = {(float)hv.x, (float)hv.y, (float)hv.z, (float)hv.w};
#pragma unroll
            for (int q = 0; q < 4; q++) {
                int k = part * HID + k4 * 4 + q;
#pragma unroll
                for (int j = 0; j < 10; j++) fma4(acc[j], xs[q], sW4[k * 10 + j]);
            }
        }
    }
    float m = -1e30f;
#pragma unroll
    for (int j = 0; j < 10; j++)
        m = fmaxf(m, fmaxf(fmaxf(acc[j].x, acc[j].y), fmaxf(acc[j].z, acc[j].w)));
    float s = 0.f;
#pragma unroll
    for (int j = 0; j < 10; j++)
        s += __expf(acc[j].x - m) + __expf(acc[j].y - m) + __expf(acc[j].z - m) + __expf(acc[j].w - m);
    float l = m + __logf(s);
    float4* orow = (float4*)(out + (size_t)r * NCLS);
#pragma unroll
    for (int j = 0; j < 10; j++) {
        float4 v = acc[j];
        v.x -= l; v.y -= l; v.z -= l; v.w -= l;
        orow[j] = v;
    }
}

// ---------- launch ----------

extern "C" void kernel_launch(void* const* d_in, const int* in_sizes, int n_in,
                              void* d_out, int out_size, void* d_ws, size_t ws_size,
                              hipStream_t stream) {
    const float* x       = (const float*)d_in[0];
    const int*   ei      = (const int*)d_in[1];
    const float* ew      = (const float*)d_in[2];
    const float* W_first = (const float*)d_in[3];
    const float* b_first = (const float*)d_in[4];
    const float* bn1_g   = (const float*)d_in[5];
    const float* bn1_b   = (const float*)d_in[6];
    const float* Wc1     = (const float*)d_in[7];
    const float* bc1     = (const float*)d_in[8];
    const float* bn2_g   = (const float*)d_in[9];
    const float* bn2_b   = (const float*)d_in[10];
    const float* Wc2     = (const float*)d_in[11];
    const float* bc2     = (const float*)d_in[12];
    const float* bn3_g   = (const float*)d_in[13];
    const float* bn3_b   = (const float*)d_in[14];
    const float* W_out   = (const float*)d_in[15];
    const float* b_out   = (const float*)d_in[16];
    float* out = (float*)d_out;

    // workspace layout — packed/stats/status/tickets contiguous for ONE memset
    char* wsb = (char*)d_ws;
    _Float16* z0h = (_Float16*)wsb;                         // N*48 fp16
    _Float16* z1h = z0h + (size_t)NN * HID;
    _Float16* z2h = z1h + (size_t)NN * HID;
    _Float16* tbh = z2h + (size_t)NN * HID;                 // dinv-scaled gather table fp16
    unsigned long long* packed = (unsigned long long*)(tbh + (size_t)NN * HID);  // N u64
    float*    stats   = (float*)(packed + NN);              // 288
    unsigned* status  = (unsigned*)(stats + 288);           // 400 (scan lookback states)
    unsigned* tickets = status + 400;                       // 4
    float*    dinv    = (float*)(tickets + 4);              // N
    int*      rank    = (int*)(dinv + NN);                  // E
    int*      row_st  = rank + EE;                          // N+4
    unsigned* es      = (unsigned*)(row_st + NN + 4);       // E u32 (src<<15 | ew15)

    const size_t memset_bytes = sizeof(unsigned long long) * NN + sizeof(float) * 288
                              + sizeof(unsigned) * 404;
    hipMemsetAsync(packed, 0, memset_bytes, stream);

    // FUSE_A: edge histogram || mm1 (LDS-free), 17:1 interleave
    f_edge_mm1<<<BLKE + BLKN, 256, 0, stream>>>(ei, ew, packed, rank, x, W_first, b_first, (half4*)z0h);
    // FUSE_B: decoupled-lookback scan (+dinv) || BN1 stats
    f_scan_stats<<<BLKN + NSTAT, 256, 0, stream>>>(packed, row_st, dinv, status, tickets, z0h, stats);
    // FUSE_C: scatter (4B packed es) || mm48#1 (inline BN1 fold) -> tbh
    f_scatter_mm48<<<BLKE + BLKN, 256, 0, stream>>>(ei, ew, row_st, rank, es,
                                                    stats, bn1_g, bn1_b, Wc1,
                                                    (const half4*)z0h, dinv, (half4*)tbh);
    // conv 1
    k_agg<<<NN / 4, 256, 0, stream>>>((const half8*)tbh, row_st, es, dinv, bc1, (half8*)z1h);
    k_stats<<<NSTAT, 256, 0, stream>>>(z1h, stats + 96);
    // conv 2
    k_mm48<<<BLKN, 256, 0, stream>>>(stats + 96, bn2_g, bn2_b, Wc2, (const half4*)z1h, dinv, (half4*)tbh);
    k_agg<<<NN / 4, 256, 0, stream>>>((const half8*)tbh, row_st, es, dinv, bc2, (half8*)z2h);
    k_stats<<<NSTAT, 256, 0, stream>>>(z2h, stats + 192);
    // output layer (BN1/2/3 folded inline) + log_softmax
    k_final<<<BLKN, 256, 0, stream>>>((const half4*)z0h, (const half4*)z1h, (const half4*)z2h,
                                      stats, bn1_g, bn1_b, bn2_g, bn2_b, bn3_g, bn3_b,
                                      W_out, b_out, out);
}